// Round 14
// baseline (433.569 us; speedup 1.0000x reference)
//
#include <hip/hip_runtime.h>
#include <hip/hip_bf16.h>

// Problem constants
#define BB 8
#define NN 4096
#define CC 384
#define HH 8
#define DD 48
#define TT (BB*NN)        // 32768 tokens
#define CAP (TT + 128)    // two-ended perm region, 128-row pad gap
#define NROWT (CAP/128)   // 257 row tiles
#define NQ ((size_t)BB*HH*NN*DD)   // 12582912 elements per q/k/v buffer (== TT*CC)
#define LISTCAP 32768

static_assert(CAP % 128 == 0, "cap");

typedef __attribute__((ext_vector_type(8))) short bf16x8;
typedef __attribute__((ext_vector_type(4))) float f32x4;

__device__ __forceinline__ float waveRedSum(float v){
  #pragma unroll
  for (int o = 32; o > 0; o >>= 1) v += __shfl_xor(v, o);
  return v;
}

__device__ __forceinline__ unsigned short f2bf(float f){
  unsigned u = __float_as_uint(f);
  u += 0x7FFFu + ((u >> 16) & 1u);
  return (unsigned short)(u >> 16);
}
__device__ __forceinline__ float bf2f(unsigned short h){
  return __uint_as_float(((unsigned)h) << 16);
}

// -------------------- setup: perm/cur init + all 4 weight splits, one dispatch
__global__ void k_setup(const float* __restrict__ qw0, const float* __restrict__ qw1,
                        const float* __restrict__ pw0, const float* __restrict__ pw1,
                        unsigned short* __restrict__ qw0h, unsigned short* __restrict__ qw0l,
                        unsigned short* __restrict__ qw1h, unsigned short* __restrict__ qw1l,
                        unsigned short* __restrict__ pw0h, unsigned short* __restrict__ pw0l,
                        unsigned short* __restrict__ pw1h, unsigned short* __restrict__ pw1l,
                        int* __restrict__ perm0, int* __restrict__ perm1, int* __restrict__ cur){
  const int NQW = 1152*384/4, NPW = 384*384/4;
  if (blockIdx.x >= 1152){
    int i = (blockIdx.x - 1152)*256 + threadIdx.x;
    if (i < 8) cur[i] = 0;
    if (i < CAP){ perm0[i] = -1; perm1[i] = -1; }
    return;
  }
  int i = blockIdx.x*256 + threadIdx.x;
  const float* src; unsigned short* hi; unsigned short* lo; int off;
  if (i < NQW){ src = qw0; hi = qw0h; lo = qw0l; off = i; }
  else if (i < 2*NQW){ src = qw1; hi = qw1h; lo = qw1l; off = i - NQW; }
  else if (i < 2*NQW + NPW){ src = pw0; hi = pw0h; lo = pw0l; off = i - 2*NQW; }
  else if (i < 2*NQW + 2*NPW){ src = pw1; hi = pw1h; lo = pw1l; off = i - 2*NQW - NPW; }
  else return;
  float4 v = ((const float4*)src)[off];
  float f[4] = {v.x, v.y, v.z, v.w};
  unsigned short h[4], l[4];
  #pragma unroll
  for (int j = 0; j < 4; j++){
    h[j] = f2bf(f[j]);
    l[j] = f2bf(f[j] - bf2f(h[j]));   // residual exact in fp32 (Sterbenz)
  }
  uint2 hv, lv;
  hv.x = h[0] | ((unsigned)h[1] << 16); hv.y = h[2] | ((unsigned)h[3] << 16);
  lv.x = l[0] | ((unsigned)l[1] << 16); lv.y = l[2] | ((unsigned)l[3] << 16);
  ((uint2*)hi)[off] = hv;
  ((uint2*)lo)[off] = lv;
}

// --------- qkv gate + compaction scatter + FUSED x hi/lo split (proven 32-token geometry)
__global__ void k_gate_scatter(const float* __restrict__ X,
                               const float* __restrict__ gw, const float* __restrict__ gb,
                               int* __restrict__ perm, int* __restrict__ cur,
                               unsigned char* __restrict__ selb,
                               unsigned short* __restrict__ Xhi, unsigned short* __restrict__ Xlo){
  const int lane = threadIdx.x & 63;
  const int wave = threadIdx.x >> 6;
  float gd[6];
  #pragma unroll
  for (int j = 0; j < 6; j++){
    int c = lane + 64*j;
    gd[j] = gw[c*2+1] - gw[c*2];
  }
  const float gbd = gb[1] - gb[0];
  const int tok0 = (blockIdx.x*4 + wave) * 32;
  unsigned mask = 0u;
  for (int i = 0; i < 32; i++){
    const size_t rowoff = (size_t)(tok0 + i) * CC;
    const float* xr = X + rowoff;
    float d = 0.f;
    #pragma unroll
    for (int j = 0; j < 6; j++){
      float xv = xr[lane + 64*j];
      d = fmaf(xv, gd[j], d);
      unsigned short h = f2bf(xv);
      Xhi[rowoff + lane + 64*j] = h;
      Xlo[rowoff + lane + 64*j] = f2bf(xv - bf2f(h));
    }
    d = waveRedSum(d);
    if (d + gbd > 0.f) mask |= (1u << i);   // sel==1 iff l1 > l0
  }
  int n1 = __popc(mask), n0 = 32 - n1;
  int b0 = 0, b1 = 0;
  if (lane == 0){
    b0 = atomicAdd(cur + 0, n0);
    b1 = atomicAdd(cur + 1, n1);
  }
  b0 = __shfl(b0, 0); b1 = __shfl(b1, 0);
  if (lane < 32){
    int sel = (mask >> lane) & 1;
    unsigned below = mask & ((1u << lane) - 1u);
    int r1 = __popc(below);
    int r0 = lane - r1;
    int idx = sel ? (CAP - 1 - (b1 + r1)) : (b0 + r0);
    perm[idx] = tok0 + lane;
    selb[tok0 + lane] = (unsigned char)sel;
  }
}

// --------------------------------- proj gate from fused partials (fixed order)
__global__ void k_gate2(const float* __restrict__ gpart, const float* __restrict__ gb,
                        int* __restrict__ perm, int* __restrict__ cur){
  const int t = blockIdx.x*256 + threadIdx.x;
  const int lane = threadIdx.x & 63;
  const float gbd = gb[1] - gb[0];
  float4 a = ((const float4*)(gpart + (size_t)t*8))[0];
  float4 c = ((const float4*)(gpart + (size_t)t*8))[1];
  float d = ((a.x + a.y) + (a.z + a.w)) + ((c.x + c.y) + (c.z + c.w)) + gbd;
  bool sel = d > 0.f;
  unsigned long long m = __ballot(sel);
  int n1 = (int)__popcll(m);
  int b0 = 0, b1 = 0;
  if (lane == 0){
    b0 = atomicAdd(cur + 0, 64 - n1);
    b1 = atomicAdd(cur + 1, n1);
  }
  b0 = __shfl(b0, 0); b1 = __shfl(b1, 0);
  unsigned long long below = m & ((1ull << lane) - 1ull);
  int r1 = (int)__popcll(below);
  int r0 = lane - r1;
  int idx = sel ? (CAP - 1 - (b1 + r1)) : (b0 + r0);
  perm[idx] = t;
}

// ------------------------------------------------------------- MFMA MoE GEMM
// R4/R13 schedule (stage -> sync -> compute -> sync, XOR-swizzled hi staging,
// bx-fastest visit order) with ONE change for PASSES==3: lo operands are
// loaded per-lane global->VGPR (same rows/values the staging would fetch),
// drained by the same barrier. Halves LDS footprint (33->16.9 KB) and LDS
// pipe traffic; MFMA order identical -> bit-identical output.
template<int NCOLS, int PASSES, bool IS_QKV>
__global__ __launch_bounds__(256)
void k_gemm_mfma(const unsigned short* __restrict__ Ahi_g, const unsigned short* __restrict__ Alo_g,
                 const unsigned short* __restrict__ W0h, const unsigned short* __restrict__ W0l,
                 const unsigned short* __restrict__ W1h, const unsigned short* __restrict__ W1l,
                 const float* __restrict__ bias0, const float* __restrict__ bias1,
                 const int* __restrict__ perm, const int* __restrict__ cur,
                 unsigned short* __restrict__ oq, unsigned short* __restrict__ ok,
                 float* __restrict__ ov, float* __restrict__ oproj,
                 int* __restrict__ tlist, int* __restrict__ tcnt)
{
  constexpr int GDX = NCOLS / 128;
  constexpr int NWG = GDX * NROWT;
  __shared__ unsigned short As[128*32];
  __shared__ unsigned short Bs[128*32];
  __shared__ int permv[128];

  // bijective XCD-chunked swizzle (m204 form), bx-fastest within-chunk (proven)
  int orig = blockIdx.y * GDX + blockIdx.x;
  constexpr int qq = NWG >> 3, rr = NWG & 7;
  int xcd = orig & 7, slot = orig >> 3;
  int logical = (xcd < rr) ? (xcd*(qq+1) + slot) : (rr*(qq+1) + (xcd-rr)*qq + slot);
  const int bx = logical % GDX, by = logical / GDX;

  const int tid = threadIdx.x;
  const int m0 = by * 128, n0 = bx * 128;
  if (tid < 128) permv[tid] = perm[m0 + tid];
  __syncthreads();
  const int expert = (m0 > cur[0]) ? 1 : 0;
  const unsigned short* Wh = expert ? W1h : W0h;
  const unsigned short* Wl = expert ? W1l : W0l;

  // hi staging (unchanged proven pattern)
  const int c0 = tid, c1 = tid + 256;
  const int r0 = c0 >> 2, r1 = c1 >> 2;
  const int s0 = (((c0 & 3) ^ ((r0 >> 1) & 3))) * 8;
  const int s1 = (((c1 & 3) ^ ((r1 >> 1) & 3))) * 8;
  int t0 = permv[r0]; if (t0 < 0) t0 = 0;
  int t1 = permv[r1]; if (t1 < 0) t1 = 0;
  const unsigned short* a0h = Ahi_g + (size_t)t0*CC + s0;
  const unsigned short* a1h = Ahi_g + (size_t)t1*CC + s1;
  const unsigned short* b0h = Wh + (size_t)(n0 + r0)*CC + s0;
  const unsigned short* b1h = Wh + (size_t)(n0 + r1)*CC + s1;
  const int d0 = c0*8, d1 = c1*8;

  const int lane = tid & 63;
  const int wv = tid >> 6, wr = wv >> 1, wc2 = wv & 1;
  const int lr = lane & 15, lg = lane >> 4;

  // lo fragment pointers: per-lane direct global (same rows as staging would fetch)
  const unsigned short* aloP[4];
  const unsigned short* bloP[4];
  if constexpr (PASSES == 3){
    #pragma unroll
    for (int f = 0; f < 4; f++){
      int tr = permv[wr*64 + f*16 + lr]; if (tr < 0) tr = 0;
      aloP[f] = Alo_g + (size_t)tr*CC + lg*8;
      bloP[f] = Wl + (size_t)(n0 + wc2*64 + f*16 + lr)*CC + lg*8;
    }
  }

  f32x4 acc[4][4];
  #pragma unroll
  for (int i = 0; i < 4; i++)
    #pragma unroll
    for (int j = 0; j < 4; j++) acc[i][j] = (f32x4){0.f, 0.f, 0.f, 0.f};

  int aoff[4], boff[4];
  #pragma unroll
  for (int f = 0; f < 4; f++){
    int ra = wr*64 + f*16 + lr;
    aoff[f] = ra*32 + ((lg ^ ((ra >> 1) & 3)) * 8);
    int rb = wc2*64 + f*16 + lr;
    boff[f] = rb*32 + ((lg ^ ((rb >> 1) & 3)) * 8);
  }

  #define GLD(gp, lp) __builtin_amdgcn_global_load_lds( \
      (const __attribute__((address_space(1))) void*)(gp), \
      (__attribute__((address_space(3))) void*)(lp), 16, 0, 0)

  for (int ko = 0; ko < CC; ko += 32){
    bf16x8 al[4], bl[4];
    if constexpr (PASSES == 3){
      #pragma unroll
      for (int f = 0; f < 4; f++){
        al[f] = *(const bf16x8*)(aloP[f] + ko);
        bl[f] = *(const bf16x8*)(bloP[f] + ko);
      }
    }
    GLD(a0h + ko, &As[d0]);
    GLD(a1h + ko, &As[d1]);
    GLD(b0h + ko, &Bs[d0]);
    GLD(b1h + ko, &Bs[d1]);
    __syncthreads();   // drains vmcnt: hi tile in LDS, lo regs in flight/ready
    bf16x8 ah[4], bh[4];
    #pragma unroll
    for (int f = 0; f < 4; f++){
      ah[f] = *(const bf16x8*)&As[aoff[f]];
      bh[f] = *(const bf16x8*)&Bs[boff[f]];
    }
    #pragma unroll
    for (int mf = 0; mf < 4; mf++)
      #pragma unroll
      for (int nf = 0; nf < 4; nf++){
        acc[mf][nf] = __builtin_amdgcn_mfma_f32_16x16x32_bf16(ah[mf], bh[nf], acc[mf][nf], 0, 0, 0);
        if constexpr (PASSES == 3){
          acc[mf][nf] = __builtin_amdgcn_mfma_f32_16x16x32_bf16(al[mf], bh[nf], acc[mf][nf], 0, 0, 0);
          acc[mf][nf] = __builtin_amdgcn_mfma_f32_16x16x32_bf16(ah[mf], bl[nf], acc[mf][nf], 0, 0, 0);
        }
      }
    __syncthreads();
  }
  #undef GLD

  // epilogue: C/D layout col=lane&15, row=(lane>>4)*4+reg (m89-verified)
  #pragma unroll
  for (int mf = 0; mf < 4; mf++){
    #pragma unroll
    for (int j = 0; j < 4; j++){
      const int rl = wr*64 + mf*16 + lg*4 + j;
      const int t = permv[rl];
      if (t < 0) continue;
      const int b = t >> 12, nn = t & 4095;
      #pragma unroll
      for (int nf = 0; nf < 4; nf++){
        const int col = n0 + wc2*64 + nf*16 + lr;
        const float val = acc[mf][nf][j];
        if constexpr (IS_QKV){
          const int which = col / CC;
          const int rem = col - which*CC;
          const int h = rem / DD;
          const int e = rem - h*DD;
          const size_t off = (((size_t)b*HH + h)*NN + nn)*DD + e;
          if (which == 0){
            oq[off] = f2bf(val);
            if (fabsf(val) < 2.5e-5f){
              int pq = atomicAdd(tcnt, 1);
              if (pq < LISTCAP) tlist[pq] = (int)off;
            }
          } else if (which == 1){
            ok[off] = f2bf(val);
            if (fabsf(val) < 2.5e-5f){
              int pq = atomicAdd(tcnt, 1);
              if (pq < LISTCAP) tlist[pq] = (int)(off + NQ);
            }
          } else {
            ov[off] = val;
          }
        } else {
          const float* bs = expert ? bias1 : bias0;
          oproj[(size_t)t*CC + col] = val + bs[col];
        }
      }
    }
  }
}

// --------- merged: topup fix (blocks 0..63) || scales partials (blocks 64..1087)
__global__ void k_topup_scales(unsigned short* __restrict__ qb, unsigned short* __restrict__ kb,
                               const int* __restrict__ list, const int* __restrict__ cnt,
                               const float* __restrict__ x,
                               const float* __restrict__ w0, const float* __restrict__ w1,
                               const unsigned char* __restrict__ selb,
                               float* __restrict__ part){
  __shared__ float sq[256], sk[256];
  if (blockIdx.x < 64){
    const int lane = threadIdx.x & 63;
    const int gw = (blockIdx.x*256 + threadIdx.x) >> 6;
    const int nwaves = 64 * 4;
    int n = cnt[0]; if (n > LISTCAP) n = LISTCAP;
    for (int e = gw; e < n; e += nwaves){
      int idx = list[e];
      int isK = (idx >= (int)NQ);
      int li = isK ? idx - (int)NQ : idx;
      int d = li % DD; int rest = li / DD;
      int nn = rest & 4095; int bh = rest >> 12;
      int b = bh >> 3, h = bh & 7;
      int t = b*NN + nn;
      int col = (isK ? CC : 0) + h*DD + d;
      const float* w = selb[t] ? w1 : w0;
      const float* xr = x + (size_t)t*CC;
      const float* wr = w + (size_t)col*CC;
      float s = 0.f;
      #pragma unroll
      for (int j = 0; j < 6; j++) s = fmaf(xr[lane + 64*j], wr[lane + 64*j], s);
      s = waveRedSum(s);
      if (lane == 0) (isK ? kb : qb)[li] = f2bf(s);
    }
    return;
  }
  const int blk = blockIdx.x - 64;
  const int row = blk*256 + threadIdx.x;
  const uint4* qp = (const uint4*)(qb + (size_t)row*DD);
  const uint4* kp = (const uint4*)(kb + (size_t)row*DD);
  float qss = 0.f, qsa = 0.f, kss = 0.f, ksa = 0.f;
  #pragma unroll
  for (int j = 0; j < 6; j++){
    uint4 u = qp[j];
    unsigned w[4] = {u.x, u.y, u.z, u.w};
    #pragma unroll
    for (int q2 = 0; q2 < 4; q2++){
      float f0 = bf2f((unsigned short)(w[q2] & 0xFFFFu));
      float f1 = bf2f((unsigned short)(w[q2] >> 16));
      qss = fmaf(f0, f0, qss); qsa += fabsf(f0);
      qss = fmaf(f1, f1, qss); qsa += fabsf(f1);
    }
    uint4 v = kp[j];
    unsigned w2[4] = {v.x, v.y, v.z, v.w};
    #pragma unroll
    for (int q2 = 0; q2 < 4; q2++){
      float f0 = bf2f((unsigned short)(w2[q2] & 0xFFFFu));
      float f1 = bf2f((unsigned short)(w2[q2] >> 16));
      kss = fmaf(f0, f0, kss); ksa += fabsf(f0);
      kss = fmaf(f1, f1, kss); ksa += fabsf(f1);
    }
  }
  sq[threadIdx.x] = qsa / sqrtf(qss);
  sk[threadIdx.x] = ksa / sqrtf(kss);
  __syncthreads();
  for (int s = 128; s > 0; s >>= 1){
    if (threadIdx.x < s){ sq[threadIdx.x] += sq[threadIdx.x+s]; sk[threadIdx.x] += sk[threadIdx.x+s]; }
    __syncthreads();
  }
  if (threadIdx.x == 0){
    part[blk*2+0] = sq[0];
    part[blk*2+1] = sk[0];
  }
}

// --------- merged: scales final reduce (block 0) || attn partial (blocks 1..512)
__global__ void k_sred_attnp(const float* __restrict__ part_in, float* __restrict__ scalesb,
                             const unsigned short* __restrict__ kb, const float* __restrict__ vb,
                             float* __restrict__ part_out){
  if (blockIdx.x == 0){
    __shared__ float sq[256], sk[256];
    const int t = threadIdx.x;
    float aq = 0.f, ak = 0.f;
    for (int i = t; i < 1024; i += 256){ aq += part_in[2*i]; ak += part_in[2*i+1]; }
    sq[t] = aq; sk[t] = ak;
    __syncthreads();
    for (int s = 128; s > 0; s >>= 1){
      if (t < s){ sq[t] += sq[t+s]; sk[t] += sk[t+s]; }
      __syncthreads();
    }
    if (t == 0){
      scalesb[0] = sq[0] * (1.0f/12582912.0f);
      scalesb[1] = sk[0] * (1.0f/12582912.0f);
    }
    return;
  }
  __shared__ float ks[64][48];
  __shared__ float vs[64][48];
  const int idx = blockIdx.x - 1;
  const int bh = idx & 63, seg = idx >> 6;
  const int tid = threadIdx.x;
  const int ti = tid >> 5;
  const int tj = (tid >> 2) & 7;
  const int sl = tid & 3;
  const int dd0 = ti*6, ee0 = tj*6;
  const unsigned short* kbase = kb + ((size_t)bh*NN + seg*512) * DD;
  const float* vbase = vb + ((size_t)bh*NN + seg*512) * DD;
  float acc[6][6] = {};
  for (int c = 0; c < 8; c++){
    __syncthreads();
    for (int f = tid*2; f < 3072; f += 512){
      unsigned kk2 = *(const unsigned*)(kbase + c*3072 + f);
      float2 vv2 = *(const float2*)(vbase + c*3072 + f);
      (&ks[0][0])[f]   = ((short)(unsigned short)(kk2 & 0xFFFFu) > 0) ? 1.f : 0.f;
      (&ks[0][0])[f+1] = ((short)(unsigned short)(kk2 >> 16) > 0) ? 1.f : 0.f;
      (&vs[0][0])[f]   = vv2.x;
      (&vs[0][0])[f+1] = vv2.y;
    }
    __syncthreads();
    for (int nl = sl*16; nl < sl*16 + 16; nl++){
      float kk[6], vv[6];
      #pragma unroll
      for (int i = 0; i < 6; i++){ kk[i] = ks[nl][dd0+i]; vv[i] = vs[nl][ee0+i]; }
      #pragma unroll
      for (int i = 0; i < 6; i++)
        #pragma unroll
        for (int j = 0; j < 6; j++)
          acc[i][j] = fmaf(kk[i], vv[j], acc[i][j]);
    }
  }
  float* p = part_out + ((size_t)seg*64 + bh) * (DD*DD);
  #pragma unroll
  for (int i = 0; i < 6; i++)
    #pragma unroll
    for (int j = 0; j < 6; j++){
      float a = acc[i][j];
      a += __shfl_xor(a, 1);
      a += __shfl_xor(a, 2);
      if (sl == 0) p[(dd0+i)*48 + (ee0+j)] = a;
    }
}

// reduce partials, fold scale2, emit TRANSPOSED hi/lo bf16: aT[e][d], d-padded to 64
__global__ void k_attn_reduce(const float* __restrict__ part, const float* __restrict__ scalesb,
                              unsigned short* __restrict__ aTh, unsigned short* __restrict__ aTl){
  const int bh = blockIdx.x;
  const float s2 = scalesb[1];
  for (int f = threadIdx.x; f < 3072; f += 256){
    const int e = f >> 6, d = f & 63;
    float s = 0.f;
    if (d < 48){
      #pragma unroll
      for (int seg = 0; seg < 8; seg++) s += part[((size_t)seg*64 + bh)*2304 + d*48 + e];
      s *= s2;
    }
    unsigned short hi = f2bf(s);
    aTh[(size_t)bh*3072 + f] = hi;
    aTl[(size_t)bh*3072 + f] = f2bf(s - bf2f(hi));
  }
}

// ------ fused: S = qbit@attn via MFMA (S in LDS), then normalize + dconv + gate partial
__global__ __launch_bounds__(256, 4)
void k_fused(const unsigned short* __restrict__ qb, const float* __restrict__ vb,
             const unsigned short* __restrict__ aTh, const unsigned short* __restrict__ aTl,
             const float* __restrict__ scalesb, const float* __restrict__ dw,
             const float* __restrict__ pgw,
             unsigned short* __restrict__ intermh, float* __restrict__ gpart){
  __shared__ unsigned short aT[2][48*72];
  __shared__ float S_lds[128*48];
  __shared__ float wc[16];
  const int chunk = blockIdx.x;
  const int bh = blockIdx.y;
  const int b = bh >> 3, h = bh & 7;
  const int tid = threadIdx.x;
  const int lane = tid & 63, w = tid >> 6;
  const int lr = lane & 15, lg = lane >> 4;

  for (int idx = tid; idx < 384; idx += 256){
    const int e = idx >> 3, sl = idx & 7;
    *(uint4*)&aT[0][e*72 + sl*8] = *(const uint4*)(aTh + (size_t)bh*3072 + e*64 + sl*8);
    *(uint4*)&aT[1][e*72 + sl*8] = *(const uint4*)(aTl + (size_t)bh*3072 + e*64 + sl*8);
  }
  if (tid < 9) wc[tid] = dw[h*9 + tid];
  __syncthreads();

  bf16x8 afr[2][2];
  #pragma unroll
  for (int m = 0; m < 2; m++){
    #pragma unroll
    for (int ks = 0; ks < 2; ks++){
      const int d0 = ks*32 + lg*8;
      bf16x8 a = (bf16x8){0,0,0,0,0,0,0,0};
      if (d0 < 48){
        const int tok = chunk*128 + (w*2+m)*16 + lr;
        uint4 raw = *(const uint4*)(qb + ((size_t)bh*NN + tok)*DD + d0);
        unsigned wd[4] = {raw.x, raw.y, raw.z, raw.w};
        #pragma unroll
        for (int i2 = 0; i2 < 8; i2++){
          unsigned short el = (unsigned short)((wd[i2 >> 1] >> ((i2 & 1)*16)) & 0xFFFFu);
          a[i2] = ((short)el > 0) ? (short)0x3F80 : (short)0;
        }
      }
      afr[m][ks] = a;
    }
  }
  f32x4 acc[2][3];
  #pragma unroll
  for (int m = 0; m < 2; m++)
    #pragma unroll
    for (int nf = 0; nf < 3; nf++) acc[m][nf] = (f32x4){0.f,0.f,0.f,0.f};
  #pragma unroll
  for (int nf = 0; nf < 3; nf++){
    bf16x8 bhv[2], blv[2];
    #pragma unroll
    for (int ks = 0; ks < 2; ks++){
      const int bo = (nf*16 + lr)*72 + ks*32 + lg*8;
      bhv[ks] = *(const bf16x8*)&aT[0][bo];
      blv[ks] = *(const bf16x8*)&aT[1][bo];
    }
    #pragma unroll
    for (int m = 0; m < 2; m++)
      #pragma unroll
      for (int ks = 0; ks < 2; ks++){
        acc[m][nf] = __builtin_amdgcn_mfma_f32_16x16x32_bf16(afr[m][ks], bhv[ks], acc[m][nf], 0, 0, 0);
        acc[m][nf] = __builtin_amdgcn_mfma_f32_16x16x32_bf16(afr[m][ks], blv[ks], acc[m][nf], 0, 0, 0);
      }
  }
  #pragma unroll
  for (int m = 0; m < 2; m++)
    #pragma unroll
    for (int nf = 0; nf < 3; nf++)
      #pragma unroll
      for (int j = 0; j < 4; j++)
        S_lds[((w*2+m)*16 + lg*4 + j)*48 + nf*16 + lr] = acc[m][nf][j];
  __syncthreads();

  const float coef = scalesb[0] * 0.31830988618379067f;   // scale1 / pi
  const float gdh = (lane < 48) ? (pgw[(h*48+lane)*2+1] - pgw[(h*48+lane)*2]) : 0.f;
  const float* vrow = vb + (size_t)bh*NN*DD;
  const int n0 = chunk*128 + w*32;
  float ring[9];
  #pragma unroll
  for (int k2 = 0; k2 < 8; k2++){
    int nn2 = n0 - 4 + k2;
    ring[k2] = (nn2 >= 0 && nn2 < NN && lane < 48) ? vrow[(size_t)nn2*DD + lane] : 0.f;
  }
  for (int it = 0; it < 32; it++){
    const int n = n0 + it;
    const int nh = n + 4;
    ring[8] = (nh < NN && lane < 48) ? vrow[(size_t)nh*DD + lane] : 0.f;
    const float vv = ring[4];
    const float Sv = (lane < 48) ? S_lds[(w*32 + it)*48 + lane] : 0.f;
    float op = 0.5f*vv - coef*Sv;
    float ss = waveRedSum(op*op);
    float res = op / sqrtf(ss);
    float dc = 0.f;
    #pragma unroll
    for (int k2 = 0; k2 < 9; k2++) dc = fmaf(wc[k2], ring[k2], dc);
    float r = res + dc;
    if (lane < 48)
      intermh[((size_t)b*NN + n)*CC + h*DD + lane] = f2bf(r);
    float gp = waveRedSum(r*gdh);
    if (lane == 0) gpart[((size_t)b*NN + n)*8 + h] = gp;
    #pragma unroll
    for (int k2 = 0; k2 < 8; k2++) ring[k2] = ring[k2+1];
  }
}

// ---------------------------------------------------------------- launch
extern "C" void kernel_launch(void* const* d_in, const int* in_sizes, int n_in,
                              void* d_out, int out_size, void* d_ws, size_t ws_size,
                              hipStream_t stream){
  const float* x    = (const float*)d_in[0];
  const float* qgw  = (const float*)d_in[3];
  const float* qgb  = (const float*)d_in[4];
  const float* qw0  = (const float*)d_in[5];
  const float* qw1  = (const float*)d_in[6];
  const float* pgw  = (const float*)d_in[7];
  const float* pgb  = (const float*)d_in[8];
  const float* pw0  = (const float*)d_in[9];
  const float* pb0  = (const float*)d_in[10];
  const float* pw1  = (const float*)d_in[11];
  const float* pb1  = (const float*)d_in[12];
  const float* dw   = (const float*)d_in[13];
  float* out = (float*)d_out;

  char* p = (char*)d_ws;
  auto alloc = [&](size_t bytes){ char* r = p; p += (bytes + 255) & ~(size_t)255; return r; };

  unsigned short* qbuf = (unsigned short*)alloc(2*NQ);
  unsigned short* kbuf = (unsigned short*)alloc(2*NQ);
  float* vbuf          = (float*)alloc(4*NQ);
  char* xreg           = alloc(4*NQ);            // Xhi/Xlo; intermh overlays Xhi after gemm
  unsigned short* Xhi  = (unsigned short*)xreg;
  unsigned short* Xlo  = Xhi + NQ;
  unsigned short* intermh = (unsigned short*)xreg;   // [T,384] bf16 (overlays Xhi)
  unsigned short* qw0h = (unsigned short*)alloc(2*1152*384);
  unsigned short* qw0l = (unsigned short*)alloc(2*1152*384);
  unsigned short* qw1h = (unsigned short*)alloc(2*1152*384);
  unsigned short* qw1l = (unsigned short*)alloc(2*1152*384);
  unsigned short* pw0h = (unsigned short*)alloc(2*384*384);
  unsigned short* pw0l = (unsigned short*)alloc(2*384*384);
  unsigned short* pw1h = (unsigned short*)alloc(2*384*384);
  unsigned short* pw1l = (unsigned short*)alloc(2*384*384);
  float* attn_part     = (float*)alloc(4*(size_t)8*64*2304);
  unsigned short* aTh  = (unsigned short*)alloc(2*(size_t)64*3072);
  unsigned short* aTl  = (unsigned short*)alloc(2*(size_t)64*3072);
  float* scale_part    = (float*)alloc(4*2048);
  float* scalesb       = (float*)alloc(64);
  float* gpart         = (float*)alloc(4*(size_t)TT*8);
  int* perm_qkv        = (int*)alloc(4*CAP);
  int* perm_proj       = (int*)alloc(4*CAP);
  int* cur             = (int*)alloc(64);        // [0,1]=qkv cnt, [2,3]=proj cnt, [4]=topup cnt
  int* list            = (int*)alloc(4*LISTCAP);
  unsigned char* selq  = (unsigned char*)alloc(TT);

  k_setup<<<1152 + (CAP + 255)/256, 256, 0, stream>>>(
      qw0, qw1, pw0, pw1,
      qw0h, qw0l, qw1h, qw1l, pw0h, pw0l, pw1h, pw1l,
      perm_qkv, perm_proj, cur);

  k_gate_scatter<<<256, 256, 0, stream>>>(x, qgw, qgb, perm_qkv, cur, selq, Xhi, Xlo);

  {
    dim3 g(9, NROWT);
    k_gemm_mfma<1152, 3, true><<<g, 256, 0, stream>>>(
        Xhi, Xlo, qw0h, qw0l, qw1h, qw1l, nullptr, nullptr,
        perm_qkv, cur, qbuf, kbuf, vbuf, nullptr, list, cur + 4);
  }

  k_topup_scales<<<64 + 1024, 256, 0, stream>>>(qbuf, kbuf, list, cur + 4,
                                                x, qw0, qw1, selq, scale_part);

  k_sred_attnp<<<1 + 512, 256, 0, stream>>>(scale_part, scalesb, kbuf, vbuf, attn_part);

  k_attn_reduce<<<64, 256, 0, stream>>>(attn_part, scalesb, aTh, aTl);

  {
    dim3 g(32, 64);
    k_fused<<<g, 256, 0, stream>>>(qbuf, vbuf, aTh, aTl, scalesb, dw, pgw, intermh, gpart);
  }

  k_gate2<<<TT/256, 256, 0, stream>>>(gpart, pgb, perm_proj, cur + 2);

  {
    dim3 g(3, NROWT);
    k_gemm_mfma<384, 1, false><<<g, 256, 0, stream>>>(
        intermh, nullptr, pw0h, pw0l, pw1h, pw1l, pb0, pb1,
        perm_proj, cur + 2, nullptr, nullptr, nullptr, out, nullptr, nullptr);
  }
}

// Round 15
// 359.535 us; speedup vs baseline: 1.2059x; 1.2059x over previous
//
#include <hip/hip_runtime.h>
#include <hip/hip_bf16.h>

// Problem constants
#define BB 8
#define NN 4096
#define CC 384
#define HH 8
#define DD 48
#define TT (BB*NN)        // 32768 tokens
#define CAP (TT + 128)    // two-ended perm region, 128-row pad gap
#define NROWT (CAP/128)   // 257 row tiles
#define NQ ((size_t)BB*HH*NN*DD)   // 12582912 elements per q/k/v buffer (== TT*CC)
#define LISTCAP 32768

static_assert(CAP % 128 == 0, "cap");

typedef __attribute__((ext_vector_type(8))) short bf16x8;
typedef __attribute__((ext_vector_type(4))) float f32x4;

__device__ __forceinline__ float waveRedSum(float v){
  #pragma unroll
  for (int o = 32; o > 0; o >>= 1) v += __shfl_xor(v, o);
  return v;
}

__device__ __forceinline__ unsigned short f2bf(float f){
  unsigned u = __float_as_uint(f);
  u += 0x7FFFu + ((u >> 16) & 1u);
  return (unsigned short)(u >> 16);
}
__device__ __forceinline__ float bf2f(unsigned short h){
  return __uint_as_float(((unsigned)h) << 16);
}

// -------------------- setup: perm/cur init + all 4 weight splits, one dispatch
__global__ void k_setup(const float* __restrict__ qw0, const float* __restrict__ qw1,
                        const float* __restrict__ pw0, const float* __restrict__ pw1,
                        unsigned short* __restrict__ qw0h, unsigned short* __restrict__ qw0l,
                        unsigned short* __restrict__ qw1h, unsigned short* __restrict__ qw1l,
                        unsigned short* __restrict__ pw0h, unsigned short* __restrict__ pw0l,
                        unsigned short* __restrict__ pw1h, unsigned short* __restrict__ pw1l,
                        int* __restrict__ perm0, int* __restrict__ perm1, int* __restrict__ cur){
  const int NQW = 1152*384/4, NPW = 384*384/4;
  if (blockIdx.x >= 1152){
    int i = (blockIdx.x - 1152)*256 + threadIdx.x;
    if (i < 8) cur[i] = 0;
    if (i < CAP){ perm0[i] = -1; perm1[i] = -1; }
    return;
  }
  int i = blockIdx.x*256 + threadIdx.x;
  const float* src; unsigned short* hi; unsigned short* lo; int off;
  if (i < NQW){ src = qw0; hi = qw0h; lo = qw0l; off = i; }
  else if (i < 2*NQW){ src = qw1; hi = qw1h; lo = qw1l; off = i - NQW; }
  else if (i < 2*NQW + NPW){ src = pw0; hi = pw0h; lo = pw0l; off = i - 2*NQW; }
  else if (i < 2*NQW + 2*NPW){ src = pw1; hi = pw1h; lo = pw1l; off = i - 2*NQW - NPW; }
  else return;
  float4 v = ((const float4*)src)[off];
  float f[4] = {v.x, v.y, v.z, v.w};
  unsigned short h[4], l[4];
  #pragma unroll
  for (int j = 0; j < 4; j++){
    h[j] = f2bf(f[j]);
    l[j] = f2bf(f[j] - bf2f(h[j]));   // residual exact in fp32 (Sterbenz)
  }
  uint2 hv, lv;
  hv.x = h[0] | ((unsigned)h[1] << 16); hv.y = h[2] | ((unsigned)h[3] << 16);
  lv.x = l[0] | ((unsigned)l[1] << 16); lv.y = l[2] | ((unsigned)l[3] << 16);
  ((uint2*)hi)[off] = hv;
  ((uint2*)lo)[off] = lv;
}

// --------- qkv gate + compaction scatter + FUSED x hi/lo split (proven 32-token geometry)
__global__ void k_gate_scatter(const float* __restrict__ X,
                               const float* __restrict__ gw, const float* __restrict__ gb,
                               int* __restrict__ perm, int* __restrict__ cur,
                               unsigned char* __restrict__ selb,
                               unsigned short* __restrict__ Xhi, unsigned short* __restrict__ Xlo){
  const int lane = threadIdx.x & 63;
  const int wave = threadIdx.x >> 6;
  float gd[6];
  #pragma unroll
  for (int j = 0; j < 6; j++){
    int c = lane + 64*j;
    gd[j] = gw[c*2+1] - gw[c*2];
  }
  const float gbd = gb[1] - gb[0];
  const int tok0 = (blockIdx.x*4 + wave) * 32;
  unsigned mask = 0u;
  for (int i = 0; i < 32; i++){
    const size_t rowoff = (size_t)(tok0 + i) * CC;
    const float* xr = X + rowoff;
    float d = 0.f;
    #pragma unroll
    for (int j = 0; j < 6; j++){
      float xv = xr[lane + 64*j];
      d = fmaf(xv, gd[j], d);
      unsigned short h = f2bf(xv);
      Xhi[rowoff + lane + 64*j] = h;
      Xlo[rowoff + lane + 64*j] = f2bf(xv - bf2f(h));
    }
    d = waveRedSum(d);
    if (d + gbd > 0.f) mask |= (1u << i);   // sel==1 iff l1 > l0
  }
  int n1 = __popc(mask), n0 = 32 - n1;
  int b0 = 0, b1 = 0;
  if (lane == 0){
    b0 = atomicAdd(cur + 0, n0);
    b1 = atomicAdd(cur + 1, n1);
  }
  b0 = __shfl(b0, 0); b1 = __shfl(b1, 0);
  if (lane < 32){
    int sel = (mask >> lane) & 1;
    unsigned below = mask & ((1u << lane) - 1u);
    int r1 = __popc(below);
    int r0 = lane - r1;
    int idx = sel ? (CAP - 1 - (b1 + r1)) : (b0 + r0);
    perm[idx] = tok0 + lane;
    selb[tok0 + lane] = (unsigned char)sel;
  }
}

// --------------------------------- proj gate from fused partials (fixed order)
__global__ void k_gate2(const float* __restrict__ gpart, const float* __restrict__ gb,
                        int* __restrict__ perm, int* __restrict__ cur){
  const int t = blockIdx.x*256 + threadIdx.x;
  const int lane = threadIdx.x & 63;
  const float gbd = gb[1] - gb[0];
  float4 a = ((const float4*)(gpart + (size_t)t*8))[0];
  float4 c = ((const float4*)(gpart + (size_t)t*8))[1];
  float d = ((a.x + a.y) + (a.z + a.w)) + ((c.x + c.y) + (c.z + c.w)) + gbd;
  bool sel = d > 0.f;
  unsigned long long m = __ballot(sel);
  int n1 = (int)__popcll(m);
  int b0 = 0, b1 = 0;
  if (lane == 0){
    b0 = atomicAdd(cur + 0, 64 - n1);
    b1 = atomicAdd(cur + 1, n1);
  }
  b0 = __shfl(b0, 0); b1 = __shfl(b1, 0);
  unsigned long long below = m & ((1ull << lane) - 1ull);
  int r1 = (int)__popcll(below);
  int r0 = lane - r1;
  int idx = sel ? (CAP - 1 - (b1 + r1)) : (b0 + r0);
  perm[idx] = t;
}

// ------------------------------------------------------------- MFMA MoE GEMM
// PROVEN R4/R11 structure: 128x128 tile, BK=32, 4 waves, single-buffered LDS,
// stage -> sync -> compute -> sync, XOR-swizzled staging, bx-FASTEST visit
// order (x row-panels L2-hot per XCD; R12 proved bx-major thrashes x 5x).
template<int NCOLS, int PASSES, bool IS_QKV>
__global__ __launch_bounds__(256, 2)
void k_gemm_mfma(const unsigned short* __restrict__ Ahi_g, const unsigned short* __restrict__ Alo_g,
                 const unsigned short* __restrict__ W0h, const unsigned short* __restrict__ W0l,
                 const unsigned short* __restrict__ W1h, const unsigned short* __restrict__ W1l,
                 const float* __restrict__ bias0, const float* __restrict__ bias1,
                 const int* __restrict__ perm, const int* __restrict__ cur,
                 unsigned short* __restrict__ oq, unsigned short* __restrict__ ok,
                 float* __restrict__ ov, float* __restrict__ oproj,
                 int* __restrict__ tlist, int* __restrict__ tcnt)
{
  constexpr int GDX = NCOLS / 128;
  constexpr int NWG = GDX * NROWT;
  constexpr int NB = (PASSES == 3) ? 2 : 1;
  __shared__ unsigned short As[NB][128*32];
  __shared__ unsigned short Bs[NB][128*32];
  __shared__ int permv[128];

  // bijective XCD-chunked swizzle (m204 form), bx-fastest within-chunk (proven)
  int orig = blockIdx.y * GDX + blockIdx.x;
  constexpr int qq = NWG >> 3, rr = NWG & 7;
  int xcd = orig & 7, slot = orig >> 3;
  int logical = (xcd < rr) ? (xcd*(qq+1) + slot) : (rr*(qq+1) + (xcd-rr)*qq + slot);
  const int bx = logical % GDX, by = logical / GDX;

  const int tid = threadIdx.x;
  const int m0 = by * 128, n0 = bx * 128;
  if (tid < 128) permv[tid] = perm[m0 + tid];
  __syncthreads();
  const int expert = (m0 > cur[0]) ? 1 : 0;
  const unsigned short* Wh = expert ? W1h : W0h;
  const unsigned short* Wl = expert ? W1l : W0l;

  const int c0 = tid, c1 = tid + 256;
  const int r0 = c0 >> 2, r1 = c1 >> 2;
  const int s0 = (((c0 & 3) ^ ((r0 >> 1) & 3))) * 8;
  const int s1 = (((c1 & 3) ^ ((r1 >> 1) & 3))) * 8;
  int t0 = permv[r0]; if (t0 < 0) t0 = 0;
  int t1 = permv[r1]; if (t1 < 0) t1 = 0;
  const unsigned short* a0h = Ahi_g + (size_t)t0*CC + s0;
  const unsigned short* a1h = Ahi_g + (size_t)t1*CC + s1;
  const unsigned short* b0h = Wh + (size_t)(n0 + r0)*CC + s0;
  const unsigned short* b1h = Wh + (size_t)(n0 + r1)*CC + s1;
  const unsigned short* a0l = nullptr; const unsigned short* a1l = nullptr;
  const unsigned short* b0l = nullptr; const unsigned short* b1l = nullptr;
  if constexpr (PASSES == 3){
    a0l = Alo_g + (size_t)t0*CC + s0;
    a1l = Alo_g + (size_t)t1*CC + s1;
    b0l = Wl + (size_t)(n0 + r0)*CC + s0;
    b1l = Wl + (size_t)(n0 + r1)*CC + s1;
  }
  const int d0 = c0*8, d1 = c1*8;

  const int lane = tid & 63;
  const int wv = tid >> 6, wr = wv >> 1, wc2 = wv & 1;
  const int lr = lane & 15, lg = lane >> 4;

  f32x4 acc[4][4];
  #pragma unroll
  for (int i = 0; i < 4; i++)
    #pragma unroll
    for (int j = 0; j < 4; j++) acc[i][j] = (f32x4){0.f, 0.f, 0.f, 0.f};

  int aoff[4], boff[4];
  #pragma unroll
  for (int f = 0; f < 4; f++){
    int ra = wr*64 + f*16 + lr;
    aoff[f] = ra*32 + ((lg ^ ((ra >> 1) & 3)) * 8);
    int rb = wc2*64 + f*16 + lr;
    boff[f] = rb*32 + ((lg ^ ((rb >> 1) & 3)) * 8);
  }

  #define GLD(gp, lp) __builtin_amdgcn_global_load_lds( \
      (const __attribute__((address_space(1))) void*)(gp), \
      (__attribute__((address_space(3))) void*)(lp), 16, 0, 0)

  for (int ko = 0; ko < CC; ko += 32){
    GLD(a0h + ko, &As[0][d0]);
    GLD(a1h + ko, &As[0][d1]);
    GLD(b0h + ko, &Bs[0][d0]);
    GLD(b1h + ko, &Bs[0][d1]);
    if constexpr (PASSES == 3){
      GLD(a0l + ko, &As[1][d0]);
      GLD(a1l + ko, &As[1][d1]);
      GLD(b0l + ko, &Bs[1][d0]);
      GLD(b1l + ko, &Bs[1][d1]);
    }
    __syncthreads();
    bf16x8 ah[4], bh[4], al[4], bl[4];
    #pragma unroll
    for (int f = 0; f < 4; f++){
      ah[f] = *(const bf16x8*)&As[0][aoff[f]];
      bh[f] = *(const bf16x8*)&Bs[0][boff[f]];
      if constexpr (PASSES == 3){
        al[f] = *(const bf16x8*)&As[1][aoff[f]];
        bl[f] = *(const bf16x8*)&Bs[1][boff[f]];
      }
    }
    #pragma unroll
    for (int mf = 0; mf < 4; mf++)
      #pragma unroll
      for (int nf = 0; nf < 4; nf++){
        acc[mf][nf] = __builtin_amdgcn_mfma_f32_16x16x32_bf16(ah[mf], bh[nf], acc[mf][nf], 0, 0, 0);
        if constexpr (PASSES == 3){
          acc[mf][nf] = __builtin_amdgcn_mfma_f32_16x16x32_bf16(al[mf], bh[nf], acc[mf][nf], 0, 0, 0);
          acc[mf][nf] = __builtin_amdgcn_mfma_f32_16x16x32_bf16(ah[mf], bl[nf], acc[mf][nf], 0, 0, 0);
        }
      }
    __syncthreads();
  }
  #undef GLD

  // epilogue: C/D layout col=lane&15, row=(lane>>4)*4+reg (m89-verified)
  #pragma unroll
  for (int mf = 0; mf < 4; mf++){
    #pragma unroll
    for (int j = 0; j < 4; j++){
      const int rl = wr*64 + mf*16 + lg*4 + j;
      const int t = permv[rl];
      if (t < 0) continue;
      const int b = t >> 12, nn = t & 4095;
      #pragma unroll
      for (int nf = 0; nf < 4; nf++){
        const int col = n0 + wc2*64 + nf*16 + lr;
        const float val = acc[mf][nf][j];
        if constexpr (IS_QKV){
          const int which = col / CC;
          const int rem = col - which*CC;
          const int h = rem / DD;
          const int e = rem - h*DD;
          const size_t off = (((size_t)b*HH + h)*NN + nn)*DD + e;
          if (which == 0){
            oq[off] = f2bf(val);
            if (fabsf(val) < 2.5e-5f){
              int pq = atomicAdd(tcnt, 1);
              if (pq < LISTCAP) tlist[pq] = (int)off;
            }
          } else if (which == 1){
            ok[off] = f2bf(val);
            if (fabsf(val) < 2.5e-5f){
              int pq = atomicAdd(tcnt, 1);
              if (pq < LISTCAP) tlist[pq] = (int)(off + NQ);
            }
          } else {
            ov[off] = val;
          }
        } else {
          const float* bs = expert ? bias1 : bias0;
          oproj[(size_t)t*CC + col] = val + bs[col];
        }
      }
    }
  }
}

// --------- merged: topup fix (blocks 0..63) || scales partials (blocks 64..1087)
__global__ void k_topup_scales(unsigned short* __restrict__ qb, unsigned short* __restrict__ kb,
                               const int* __restrict__ list, const int* __restrict__ cnt,
                               const float* __restrict__ x,
                               const float* __restrict__ w0, const float* __restrict__ w1,
                               const unsigned char* __restrict__ selb,
                               float* __restrict__ part){
  __shared__ float sq[256], sk[256];
  if (blockIdx.x < 64){
    const int lane = threadIdx.x & 63;
    const int gw = (blockIdx.x*256 + threadIdx.x) >> 6;
    const int nwaves = 64 * 4;
    int n = cnt[0]; if (n > LISTCAP) n = LISTCAP;
    for (int e = gw; e < n; e += nwaves){
      int idx = list[e];
      int isK = (idx >= (int)NQ);
      int li = isK ? idx - (int)NQ : idx;
      int d = li % DD; int rest = li / DD;
      int nn = rest & 4095; int bh = rest >> 12;
      int b = bh >> 3, h = bh & 7;
      int t = b*NN + nn;
      int col = (isK ? CC : 0) + h*DD + d;
      const float* w = selb[t] ? w1 : w0;
      const float* xr = x + (size_t)t*CC;
      const float* wr = w + (size_t)col*CC;
      float s = 0.f;
      #pragma unroll
      for (int j = 0; j < 6; j++) s = fmaf(xr[lane + 64*j], wr[lane + 64*j], s);
      s = waveRedSum(s);
      if (lane == 0) (isK ? kb : qb)[li] = f2bf(s);
    }
    return;
  }
  const int blk = blockIdx.x - 64;
  const int row = blk*256 + threadIdx.x;
  const uint4* qp = (const uint4*)(qb + (size_t)row*DD);
  const uint4* kp = (const uint4*)(kb + (size_t)row*DD);
  float qss = 0.f, qsa = 0.f, kss = 0.f, ksa = 0.f;
  #pragma unroll
  for (int j = 0; j < 6; j++){
    uint4 u = qp[j];
    unsigned w[4] = {u.x, u.y, u.z, u.w};
    #pragma unroll
    for (int q2 = 0; q2 < 4; q2++){
      float f0 = bf2f((unsigned short)(w[q2] & 0xFFFFu));
      float f1 = bf2f((unsigned short)(w[q2] >> 16));
      qss = fmaf(f0, f0, qss); qsa += fabsf(f0);
      qss = fmaf(f1, f1, qss); qsa += fabsf(f1);
    }
    uint4 v = kp[j];
    unsigned w2[4] = {v.x, v.y, v.z, v.w};
    #pragma unroll
    for (int q2 = 0; q2 < 4; q2++){
      float f0 = bf2f((unsigned short)(w2[q2] & 0xFFFFu));
      float f1 = bf2f((unsigned short)(w2[q2] >> 16));
      kss = fmaf(f0, f0, kss); ksa += fabsf(f0);
      kss = fmaf(f1, f1, kss); ksa += fabsf(f1);
    }
  }
  sq[threadIdx.x] = qsa / sqrtf(qss);
  sk[threadIdx.x] = ksa / sqrtf(kss);
  __syncthreads();
  for (int s = 128; s > 0; s >>= 1){
    if (threadIdx.x < s){ sq[threadIdx.x] += sq[threadIdx.x+s]; sk[threadIdx.x] += sk[threadIdx.x+s]; }
    __syncthreads();
  }
  if (threadIdx.x == 0){
    part[blk*2+0] = sq[0];
    part[blk*2+1] = sk[0];
  }
}

// --------- merged: scales final reduce (block 0) || attn partial (blocks 1..512)
__global__ void k_sred_attnp(const float* __restrict__ part_in, float* __restrict__ scalesb,
                             const unsigned short* __restrict__ kb, const float* __restrict__ vb,
                             float* __restrict__ part_out){
  if (blockIdx.x == 0){
    __shared__ float sq[256], sk[256];
    const int t = threadIdx.x;
    float aq = 0.f, ak = 0.f;
    for (int i = t; i < 1024; i += 256){ aq += part_in[2*i]; ak += part_in[2*i+1]; }
    sq[t] = aq; sk[t] = ak;
    __syncthreads();
    for (int s = 128; s > 0; s >>= 1){
      if (t < s){ sq[t] += sq[t+s]; sk[t] += sk[t+s]; }
      __syncthreads();
    }
    if (t == 0){
      scalesb[0] = sq[0] * (1.0f/12582912.0f);
      scalesb[1] = sk[0] * (1.0f/12582912.0f);
    }
    return;
  }
  __shared__ float ks[64][48];
  __shared__ float vs[64][48];
  const int idx = blockIdx.x - 1;
  const int bh = idx & 63, seg = idx >> 6;
  const int tid = threadIdx.x;
  const int ti = tid >> 5;
  const int tj = (tid >> 2) & 7;
  const int sl = tid & 3;
  const int dd0 = ti*6, ee0 = tj*6;
  const unsigned short* kbase = kb + ((size_t)bh*NN + seg*512) * DD;
  const float* vbase = vb + ((size_t)bh*NN + seg*512) * DD;
  float acc[6][6] = {};
  for (int c = 0; c < 8; c++){
    __syncthreads();
    for (int f = tid*2; f < 3072; f += 512){
      unsigned kk2 = *(const unsigned*)(kbase + c*3072 + f);
      float2 vv2 = *(const float2*)(vbase + c*3072 + f);
      (&ks[0][0])[f]   = ((short)(unsigned short)(kk2 & 0xFFFFu) > 0) ? 1.f : 0.f;
      (&ks[0][0])[f+1] = ((short)(unsigned short)(kk2 >> 16) > 0) ? 1.f : 0.f;
      (&vs[0][0])[f]   = vv2.x;
      (&vs[0][0])[f+1] = vv2.y;
    }
    __syncthreads();
    for (int nl = sl*16; nl < sl*16 + 16; nl++){
      float kk[6], vv[6];
      #pragma unroll
      for (int i = 0; i < 6; i++){ kk[i] = ks[nl][dd0+i]; vv[i] = vs[nl][ee0+i]; }
      #pragma unroll
      for (int i = 0; i < 6; i++)
        #pragma unroll
        for (int j = 0; j < 6; j++)
          acc[i][j] = fmaf(kk[i], vv[j], acc[i][j]);
    }
  }
  float* p = part_out + ((size_t)seg*64 + bh) * (DD*DD);
  #pragma unroll
  for (int i = 0; i < 6; i++)
    #pragma unroll
    for (int j = 0; j < 6; j++){
      float a = acc[i][j];
      a += __shfl_xor(a, 1);
      a += __shfl_xor(a, 2);
      if (sl == 0) p[(dd0+i)*48 + (ee0+j)] = a;
    }
}

// reduce partials, fold scale2, emit TRANSPOSED hi/lo bf16: aT[e][d], d-padded to 64
__global__ void k_attn_reduce(const float* __restrict__ part, const float* __restrict__ scalesb,
                              unsigned short* __restrict__ aTh, unsigned short* __restrict__ aTl){
  const int bh = blockIdx.x;
  const float s2 = scalesb[1];
  for (int f = threadIdx.x; f < 3072; f += 256){
    const int e = f >> 6, d = f & 63;
    float s = 0.f;
    if (d < 48){
      #pragma unroll
      for (int seg = 0; seg < 8; seg++) s += part[((size_t)seg*64 + bh)*2304 + d*48 + e];
      s *= s2;
    }
    unsigned short hi = f2bf(s);
    aTh[(size_t)bh*3072 + f] = hi;
    aTl[(size_t)bh*3072 + f] = f2bf(s - bf2f(hi));
  }
}

// ------ fused: S = qbit@attn via MFMA (S in LDS), then normalize + dconv + gate partial
__global__ __launch_bounds__(256, 4)
void k_fused(const unsigned short* __restrict__ qb, const float* __restrict__ vb,
             const unsigned short* __restrict__ aTh, const unsigned short* __restrict__ aTl,
             const float* __restrict__ scalesb, const float* __restrict__ dw,
             const float* __restrict__ pgw,
             unsigned short* __restrict__ intermh, float* __restrict__ gpart){
  __shared__ unsigned short aT[2][48*72];
  __shared__ float S_lds[128*48];
  __shared__ float wc[16];
  const int chunk = blockIdx.x;
  const int bh = blockIdx.y;
  const int b = bh >> 3, h = bh & 7;
  const int tid = threadIdx.x;
  const int lane = tid & 63, w = tid >> 6;
  const int lr = lane & 15, lg = lane >> 4;

  for (int idx = tid; idx < 384; idx += 256){
    const int e = idx >> 3, sl = idx & 7;
    *(uint4*)&aT[0][e*72 + sl*8] = *(const uint4*)(aTh + (size_t)bh*3072 + e*64 + sl*8);
    *(uint4*)&aT[1][e*72 + sl*8] = *(const uint4*)(aTl + (size_t)bh*3072 + e*64 + sl*8);
  }
  if (tid < 9) wc[tid] = dw[h*9 + tid];
  __syncthreads();

  bf16x8 afr[2][2];
  #pragma unroll
  for (int m = 0; m < 2; m++){
    #pragma unroll
    for (int ks = 0; ks < 2; ks++){
      const int d0 = ks*32 + lg*8;
      bf16x8 a = (bf16x8){0,0,0,0,0,0,0,0};
      if (d0 < 48){
        const int tok = chunk*128 + (w*2+m)*16 + lr;
        uint4 raw = *(const uint4*)(qb + ((size_t)bh*NN + tok)*DD + d0);
        unsigned wd[4] = {raw.x, raw.y, raw.z, raw.w};
        #pragma unroll
        for (int i2 = 0; i2 < 8; i2++){
          unsigned short el = (unsigned short)((wd[i2 >> 1] >> ((i2 & 1)*16)) & 0xFFFFu);
          a[i2] = ((short)el > 0) ? (short)0x3F80 : (short)0;
        }
      }
      afr[m][ks] = a;
    }
  }
  f32x4 acc[2][3];
  #pragma unroll
  for (int m = 0; m < 2; m++)
    #pragma unroll
    for (int nf = 0; nf < 3; nf++) acc[m][nf] = (f32x4){0.f,0.f,0.f,0.f};
  #pragma unroll
  for (int nf = 0; nf < 3; nf++){
    bf16x8 bhv[2], blv[2];
    #pragma unroll
    for (int ks = 0; ks < 2; ks++){
      const int bo = (nf*16 + lr)*72 + ks*32 + lg*8;
      bhv[ks] = *(const bf16x8*)&aT[0][bo];
      blv[ks] = *(const bf16x8*)&aT[1][bo];
    }
    #pragma unroll
    for (int m = 0; m < 2; m++)
      #pragma unroll
      for (int ks = 0; ks < 2; ks++){
        acc[m][nf] = __builtin_amdgcn_mfma_f32_16x16x32_bf16(afr[m][ks], bhv[ks], acc[m][nf], 0, 0, 0);
        acc[m][nf] = __builtin_amdgcn_mfma_f32_16x16x32_bf16(afr[m][ks], blv[ks], acc[m][nf], 0, 0, 0);
      }
  }
  #pragma unroll
  for (int m = 0; m < 2; m++)
    #pragma unroll
    for (int nf = 0; nf < 3; nf++)
      #pragma unroll
      for (int j = 0; j < 4; j++)
        S_lds[((w*2+m)*16 + lg*4 + j)*48 + nf*16 + lr] = acc[m][nf][j];
  __syncthreads();

  const float coef = scalesb[0] * 0.31830988618379067f;   // scale1 / pi
  const float gdh = (lane < 48) ? (pgw[(h*48+lane)*2+1] - pgw[(h*48+lane)*2]) : 0.f;
  const float* vrow = vb + (size_t)bh*NN*DD;
  const int n0 = chunk*128 + w*32;
  float ring[9];
  #pragma unroll
  for (int k2 = 0; k2 < 8; k2++){
    int nn2 = n0 - 4 + k2;
    ring[k2] = (nn2 >= 0 && nn2 < NN && lane < 48) ? vrow[(size_t)nn2*DD + lane] : 0.f;
  }
  for (int it = 0; it < 32; it++){
    const int n = n0 + it;
    const int nh = n + 4;
    ring[8] = (nh < NN && lane < 48) ? vrow[(size_t)nh*DD + lane] : 0.f;
    const float vv = ring[4];
    const float Sv = (lane < 48) ? S_lds[(w*32 + it)*48 + lane] : 0.f;
    float op = 0.5f*vv - coef*Sv;
    float ss = waveRedSum(op*op);
    float res = op / sqrtf(ss);
    float dc = 0.f;
    #pragma unroll
    for (int k2 = 0; k2 < 9; k2++) dc = fmaf(wc[k2], ring[k2], dc);
    float r = res + dc;
    if (lane < 48)
      intermh[((size_t)b*NN + n)*CC + h*DD + lane] = f2bf(r);
    float gp = waveRedSum(r*gdh);
    if (lane == 0) gpart[((size_t)b*NN + n)*8 + h] = gp;
    #pragma unroll
    for (int k2 = 0; k2 < 8; k2++) ring[k2] = ring[k2+1];
  }
}

// ---------------------------------------------------------------- launch
extern "C" void kernel_launch(void* const* d_in, const int* in_sizes, int n_in,
                              void* d_out, int out_size, void* d_ws, size_t ws_size,
                              hipStream_t stream){
  const float* x    = (const float*)d_in[0];
  const float* qgw  = (const float*)d_in[3];
  const float* qgb  = (const float*)d_in[4];
  const float* qw0  = (const float*)d_in[5];
  const float* qw1  = (const float*)d_in[6];
  const float* pgw  = (const float*)d_in[7];
  const float* pgb  = (const float*)d_in[8];
  const float* pw0  = (const float*)d_in[9];
  const float* pb0  = (const float*)d_in[10];
  const float* pw1  = (const float*)d_in[11];
  const float* pb1  = (const float*)d_in[12];
  const float* dw   = (const float*)d_in[13];
  float* out = (float*)d_out;

  char* p = (char*)d_ws;
  auto alloc = [&](size_t bytes){ char* r = p; p += (bytes + 255) & ~(size_t)255; return r; };

  unsigned short* qbuf = (unsigned short*)alloc(2*NQ);
  unsigned short* kbuf = (unsigned short*)alloc(2*NQ);
  float* vbuf          = (float*)alloc(4*NQ);
  char* xreg           = alloc(4*NQ);            // Xhi/Xlo; intermh overlays Xhi after gemm
  unsigned short* Xhi  = (unsigned short*)xreg;
  unsigned short* Xlo  = Xhi + NQ;
  unsigned short* intermh = (unsigned short*)xreg;   // [T,384] bf16 (overlays Xhi)
  unsigned short* qw0h = (unsigned short*)alloc(2*1152*384);
  unsigned short* qw0l = (unsigned short*)alloc(2*1152*384);
  unsigned short* qw1h = (unsigned short*)alloc(2*1152*384);
  unsigned short* qw1l = (unsigned short*)alloc(2*1152*384);
  unsigned short* pw0h = (unsigned short*)alloc(2*384*384);
  unsigned short* pw0l = (unsigned short*)alloc(2*384*384);
  unsigned short* pw1h = (unsigned short*)alloc(2*384*384);
  unsigned short* pw1l = (unsigned short*)alloc(2*384*384);
  float* attn_part     = (float*)alloc(4*(size_t)8*64*2304);
  unsigned short* aTh  = (unsigned short*)alloc(2*(size_t)64*3072);
  unsigned short* aTl  = (unsigned short*)alloc(2*(size_t)64*3072);
  float* scale_part    = (float*)alloc(4*2048);
  float* scalesb       = (float*)alloc(64);
  float* gpart         = (float*)alloc(4*(size_t)TT*8);
  int* perm_qkv        = (int*)alloc(4*CAP);
  int* perm_proj       = (int*)alloc(4*CAP);
  int* cur             = (int*)alloc(64);        // [0,1]=qkv cnt, [2,3]=proj cnt, [4]=topup cnt
  int* list            = (int*)alloc(4*LISTCAP);
  unsigned char* selq  = (unsigned char*)alloc(TT);

  k_setup<<<1152 + (CAP + 255)/256, 256, 0, stream>>>(
      qw0, qw1, pw0, pw1,
      qw0h, qw0l, qw1h, qw1l, pw0h, pw0l, pw1h, pw1l,
      perm_qkv, perm_proj, cur);

  k_gate_scatter<<<256, 256, 0, stream>>>(x, qgw, qgb, perm_qkv, cur, selq, Xhi, Xlo);

  {
    dim3 g(9, NROWT);
    k_gemm_mfma<1152, 3, true><<<g, 256, 0, stream>>>(
        Xhi, Xlo, qw0h, qw0l, qw1h, qw1l, nullptr, nullptr,
        perm_qkv, cur, qbuf, kbuf, vbuf, nullptr, list, cur + 4);
  }

  k_topup_scales<<<64 + 1024, 256, 0, stream>>>(qbuf, kbuf, list, cur + 4,
                                                x, qw0, qw1, selq, scale_part);

  k_sred_attnp<<<1 + 512, 256, 0, stream>>>(scale_part, scalesb, kbuf, vbuf, attn_part);

  k_attn_reduce<<<64, 256, 0, stream>>>(attn_part, scalesb, aTh, aTl);

  {
    dim3 g(32, 64);
    k_fused<<<g, 256, 0, stream>>>(qbuf, vbuf, aTh, aTl, scalesb, dw, pgw, intermh, gpart);
  }

  k_gate2<<<TT/256, 256, 0, stream>>>(gpart, pgb, perm_proj, cur + 2);

  {
    dim3 g(3, NROWT);
    k_gemm_mfma<384, 1, false><<<g, 256, 0, stream>>>(
        intermh, nullptr, pw0h, pw0l, pw1h, pw1l, pb0, pb1,
        perm_proj, cur + 2, nullptr, nullptr, nullptr, out, nullptr, nullptr);
  }
}